// Round 10
// baseline (130.213 us; speedup 1.0000x reference)
//
#include <hip/hip_runtime.h>
#include <hip/hip_bf16.h>

#define NN 4096
#define FD 128
#define NDIM 2
#define CAP 256

typedef unsigned long long u64;

// ---------- workspace layout (float offsets) ----------
// hmat [2][3][4096][128] fp32 : q=0 X@Ws (h_s), q=1 X@Wu, q=2 X@Wd
// svec [2][4][4096]           : v=0 s1u, 1 s2u, 2 s1d, 3 s2d
// hp   [2][4][4096][128] fp32 : split-K partials of L@h0
// h0T  [2][128][4096] f16     : (X@Wp) transposed, f16 (B operand of L-GEMM)
// mask [2][2][4096][64] u64   : bit-packed adjacency (bit l of word w: col=(w>>2)*256+4l+(w&3))
#define OFF_HMAT 0
#define OFF_SVEC 3145728
#define OFF_HP   3178496
#define OFF_H0T  7372800
#define OFF_MASK 7897088

typedef _Float16 f16x8 __attribute__((ext_vector_type(8)));
typedef float f32x4 __attribute__((ext_vector_type(4)));
typedef float f32x4v __attribute__((ext_vector_type(4)));
typedef unsigned long long u64x2 __attribute__((ext_vector_type(2)));

union P4 { _Float16 h[4]; int2 i2; };

__device__ __forceinline__ float f4get(const float4& v, int j) {
    return j == 0 ? v.x : j == 1 ? v.y : j == 2 ? v.z : v.w;
}

// ---------------- K1: MFMA f16 GEMM  h = X @ W_p, tile 64x128, K=128 --------
// p==0 -> h0T f16 transposed; p>=1 -> hmat fp32 slot p-1; p==2,3 also fold in
// svec = h @ a (per-row dot via lr-group shfl reduction).
__global__ __launch_bounds__(256) void k_xw(
    const float* __restrict__ X, const float* __restrict__ Wp,
    const float* __restrict__ Wsm, const float* __restrict__ Wu,
    const float* __restrict__ Wd, const float* __restrict__ au1,
    const float* __restrict__ au2, const float* __restrict__ ad1,
    const float* __restrict__ ad2, float* __restrict__ hmat,
    _Float16* __restrict__ h0T, float* __restrict__ svec) {
  int d = blockIdx.z, p = blockIdx.y;
  int r0 = blockIdx.x * 64;
  const float* W = (p == 0 ? Wp : p == 1 ? Wsm : p == 2 ? Wu : Wd) + (size_t)d * FD * FD;
  const float* Xd = X + ((size_t)d * NN + r0) * FD;
  __shared__ int4 As4[1024];  // 16 KB: X[64 rows][128 k] f16, swizzled
  __shared__ int4 Bs4[2048];  // 32 KB: Wt[128 n][128 k] f16, swizzled
  char* As = (char*)As4; char* Bs = (char*)Bs4;
  int t = threadIdx.x;

  // stage X tile 64x128 fp32 -> f16 (8 float4/thread)
#pragma unroll 4
  for (int u = 0; u < 8; u++) {
    int id = t + u * 256;
    int row = id >> 5, k4 = (id & 31) * 4;
    float4 v = *(const float4*)(Xd + (size_t)row * FD + k4);
    P4 pk;
    pk.h[0] = (_Float16)v.x; pk.h[1] = (_Float16)v.y;
    pk.h[2] = (_Float16)v.z; pk.h[3] = (_Float16)v.w;
    int off = (row * 256 + k4 * 2) ^ ((row & 7) << 4);
    *(int2*)(As + off) = pk.i2;
  }
  // stage W [k][n] fp32 -> Wt[n][k] f16 (transpose via scalar b16 writes)
#pragma unroll 4
  for (int u = 0; u < 16; u++) {
    int id = t + u * 256;
    int k = id >> 5, n4 = (id & 31) * 4;
    float4 v = *(const float4*)(W + (size_t)k * FD + n4);
#pragma unroll
    for (int j = 0; j < 4; j++) {
      int n = n4 + j;
      int off = (n * 256 + k * 2) ^ ((n & 7) << 4);
      *(_Float16*)(Bs + off) = (_Float16)f4get(v, j);
    }
  }
  __syncthreads();

  int w = t >> 6, l = t & 63;
  int lr = l & 15, lkb = (l >> 4) * 16;
  f32x4 acc[8] = {};
#pragma unroll
  for (int kb = 0; kb < 4; kb++) {
    int row = w * 16 + lr;
    int offA = (row * 256 + kb * 64 + lkb) ^ ((row & 7) << 4);
    f16x8 a = *(const f16x8*)(As + offA);
    f16x8 b[8];
#pragma unroll
    for (int n = 0; n < 8; n++) {
      int rn = n * 16 + lr;
      int off = (rn * 256 + kb * 64 + lkb) ^ ((rn & 7) << 4);
      b[n] = *(const f16x8*)(Bs + off);
    }
#pragma unroll
    for (int n = 0; n < 8; n++)
      acc[n] = __builtin_amdgcn_mfma_f32_16x16x32_f16(a, b[n], acc[n], 0, 0, 0);
  }

  if (p == 0) {
    _Float16* hT = h0T + (size_t)d * FD * NN;
#pragma unroll
    for (int n = 0; n < 8; n++) {
      int col = n * 16 + lr;
      int grow = r0 + w * 16 + (l >> 4) * 4;
      P4 pk;
#pragma unroll
      for (int r = 0; r < 4; r++) pk.h[r] = (_Float16)acc[n][r];
      *(int2*)(hT + (size_t)col * NN + grow) = pk.i2;
    }
  } else {
    float* o = hmat + ((size_t)(d * 3 + p - 1) * NN + r0) * FD;
#pragma unroll
    for (int n = 0; n < 8; n++)
#pragma unroll
      for (int r = 0; r < 4; r++)
        o[(size_t)(w * 16 + (l >> 4) * 4 + r) * FD + n * 16 + lr] = acc[n][r];
    if (p >= 2) {
      // fold svec: s1/s2 = h @ a1/a2 per row
      const float* a1 = (p == 2 ? au1 : ad1) + (size_t)d * FD;
      const float* a2 = (p == 2 ? au2 : ad2) + (size_t)d * FD;
      float av1[8], av2[8];
#pragma unroll
      for (int n = 0; n < 8; n++) {
        av1[n] = a1[n * 16 + lr];
        av2[n] = a2[n * 16 + lr];
      }
      int vb = (d * 4 + (p - 2) * 2);
#pragma unroll
      for (int r = 0; r < 4; r++) {
        float p1 = 0.0f, p2 = 0.0f;
#pragma unroll
        for (int n = 0; n < 8; n++) {
          p1 += acc[n][r] * av1[n];
          p2 += acc[n][r] * av2[n];
        }
#pragma unroll
        for (int o2 = 1; o2 < 16; o2 <<= 1) {
          p1 += __shfl_xor(p1, o2);
          p2 += __shfl_xor(p2, o2);
        }
        if (lr == 0) {
          int row = r0 + w * 16 + (l >> 4) * 4 + r;
          svec[(size_t)vb * NN + row] = p1;
          svec[(size_t)(vb + 1) * NN + row] = p2;
        }
      }
    }
  }
}

// ---------------- K2: fused lgemm + pack (block specialization) -------------
// blocks [0,512)    : hp[d][ks] = L[d][:,slice] @ h0[slice,:]  (BM=64, BK=32, nt L)
// blocks [512,8704) : bit-pack adjacency; wave = one 8 KB half-row, nt
__global__ __launch_bounds__(256) void k_mega(
    const float* __restrict__ L, const _Float16* __restrict__ h0T,
    float* __restrict__ hp,
    const float* __restrict__ Lu, const float* __restrict__ Ldn,
    u64* __restrict__ mask) {
  __shared__ int4 sm4[768];  // 12 KB (lgemm path only): As 4 KB + Bs 8 KB
  int t = threadIdx.x, w = t >> 6, lane = t & 63;

  if (blockIdx.x < 512) {
    // ---------------- lgemm path (BK=32) ----------------
    int b = blockIdx.x;
    int r0 = (b & 63) * 64, ks = (b >> 6) & 3, d = b >> 8;
    const float* Lr = L + (size_t)d * NN * NN;
    const _Float16* hT = h0T + (size_t)d * FD * NN;
    char* As = (char*)sm4;            //  4 KB: A[64 rows][32 k] f16
    char* Bs = (char*)(sm4 + 256);    //  8 KB: Bt[128 n][32 k] f16
    int lr = lane & 15, lkb = (lane >> 4) * 16;
    f32x4 acc[8] = {};
    int kbeg = ks * 1024;
    for (int kk = kbeg; kk < kbeg + 1024; kk += 32) {
#pragma unroll
      for (int u = 0; u < 2; u++) {
        int id = t + u * 256;
        int row = id >> 3, k4 = (id & 7) * 4;
        f32x4v v = __builtin_nontemporal_load(
            (const f32x4v*)(Lr + (size_t)(r0 + row) * NN + kk) + (k4 >> 2));
        P4 pk;
        pk.h[0] = (_Float16)v[0]; pk.h[1] = (_Float16)v[1];
        pk.h[2] = (_Float16)v[2]; pk.h[3] = (_Float16)v[3];
        int off = (row * 64 + k4 * 2) ^ ((row & 3) << 4);
        *(int2*)(As + off) = pk.i2;
      }
#pragma unroll
      for (int u = 0; u < 2; u++) {
        int id = t + u * 256;
        int n = id >> 2, k8 = (id & 3) * 8;
        int4 v = *(const int4*)(hT + (size_t)n * NN + kk + k8);
        int off = (n * 64 + k8 * 2) ^ ((n & 3) << 4);
        *(int4*)(Bs + off) = v;
      }
      __syncthreads();
      {
        int row = w * 16 + lr;
        int offA = (row * 64 + lkb) ^ ((row & 3) << 4);
        f16x8 a = *(const f16x8*)(As + offA);
        f16x8 bb[8];
#pragma unroll
        for (int n = 0; n < 8; n++) {
          int rn = n * 16 + lr;
          int off = (rn * 64 + lkb) ^ ((rn & 3) << 4);
          bb[n] = *(const f16x8*)(Bs + off);
        }
#pragma unroll
        for (int n = 0; n < 8; n++)
          acc[n] = __builtin_amdgcn_mfma_f32_16x16x32_f16(a, bb[n], acc[n], 0, 0, 0);
      }
      __syncthreads();
    }
    float* o = hp + ((size_t)(d * 4 + ks) * NN + r0) * FD;
#pragma unroll
    for (int n = 0; n < 8; n++)
#pragma unroll
      for (int r = 0; r < 4; r++)
        o[(size_t)(w * 16 + (lane >> 4) * 4 + r) * FD + n * 16 + lr] = acc[n][r];
    return;
  }

  // ---------------- pack path: wave = one half-row (2048 cols, 8 KB) -------
  int hr = (blockIdx.x - 512) * 4 + w;       // [0, 32768)
  int p = hr >> 13;                          // plane: d = p>>1, a = p&1
  int rq = hr & 8191;
  int row = rq >> 1, half = rq & 1;
  const float* src = ((p & 1) ? Ldn : Lu) +
                     ((size_t)(p >> 1) * NN + row) * (size_t)NN + half * 2048;
  f32x4v v[8];
#pragma unroll
  for (int q = 0; q < 4; q++) {
    const f32x4v* s4 = (const f32x4v*)(src + q * 512);
    v[2 * q]     = __builtin_nontemporal_load(s4 + lane);
    v[2 * q + 1] = __builtin_nontemporal_load(s4 + 64 + lane);
  }
  u64* o = mask + ((size_t)p * NN + row) * 64 + half * 32;
#pragma unroll
  for (int q = 0; q < 4; q++) {
    u64 m0 = __ballot(v[2 * q][0] == 1.0f);
    u64 m1 = __ballot(v[2 * q][1] == 1.0f);
    u64 m2 = __ballot(v[2 * q][2] == 1.0f);
    u64 m3 = __ballot(v[2 * q][3] == 1.0f);
    u64 m4 = __ballot(v[2 * q + 1][0] == 1.0f);
    u64 m5 = __ballot(v[2 * q + 1][1] == 1.0f);
    u64 m6 = __ballot(v[2 * q + 1][2] == 1.0f);
    u64 m7 = __ballot(v[2 * q + 1][3] == 1.0f);
    if (lane == 0) {
      u64x2 a0 = {m0, m1}, a1 = {m2, m3}, a2 = {m4, m5}, a3 = {m6, m7};
      __builtin_nontemporal_store(a0, (u64x2*)(o + q * 8 + 0));
      __builtin_nontemporal_store(a1, (u64x2*)(o + q * 8 + 2));
      __builtin_nontemporal_store(a2, (u64x2*)(o + q * 8 + 4));
      __builtin_nontemporal_store(a3, (u64x2*)(o + q * 8 + 6));
    }
  }
}

// ---------------- K3: GAT (both adjacencies) + combine, wave per row -------
__global__ __launch_bounds__(256) void k_gatc(
    const u64* __restrict__ mask, const float* __restrict__ hmat,
    const float* __restrict__ svec, const float* __restrict__ hp,
    float* __restrict__ out) {
  int d = blockIdx.y;
  int w = threadIdx.x >> 6, lane = threadIdx.x & 63;
  int i = blockIdx.x * 4 + w;

  __shared__ int ej[4][2][CAP];
  __shared__ float wt[4][2][CAP];

  // prefetch both planes' mask words (one HBM wait instead of two)
  u64 mm0 = mask[((size_t)((d * 2 + 0) * NN) + i) * 64 + lane];
  u64 mm1 = mask[((size_t)((d * 2 + 1) * NN) + i) * 64 + lane];

  float ga[2][2];  // [a][half]
#pragma unroll
  for (int a = 0; a < 2; a++) {
    const float* h = hmat + (size_t)(d * 3 + 1 + a) * NN * FD;
    const float* s1 = svec + (size_t)(d * 4 + 2 * a) * NN;
    const float* s2 = svec + (size_t)(d * 4 + 2 * a + 1) * NN;

    // --- decode: lane l owns word l; prefix-sum counts; extract bits ---
    u64 m = a == 0 ? mm0 : mm1;
    int c = __popcll(m);
    int pre = c;
#pragma unroll
    for (int o = 1; o < 64; o <<= 1) {
      int tv = __shfl_up(pre, o);
      if (lane >= o) pre += tv;
    }
    int cnt = __shfl(pre, 63);
    int base = pre - c;
    int colbase = (lane >> 2) * 256 + (lane & 3);
    while (m) {
      int b = __ffsll((unsigned long long)m) - 1;
      m &= m - 1;
      if (base < CAP) ej[w][a][base] = colbase + b * 4;
      base++;
    }
    cnt = min(cnt, CAP);

    // --- softmax over edges ---
    float s1i = s1[i];
    float mx = -1e30f;
    for (int e0 = 0; e0 < cnt; e0 += 64) {
      int e = e0 + lane;
      float sc = -1e30f;
      if (e < cnt) {
        int j = ej[w][a][e];
        float x = s1i + s2[j];
        sc = x > 0.0f ? x : 0.01f * x;
        wt[w][a][e] = sc;
      }
      mx = fmaxf(mx, sc);
    }
#pragma unroll
    for (int o = 1; o < 64; o <<= 1) mx = fmaxf(mx, __shfl_xor(mx, o));
    float sum = 0.0f;
    for (int e0 = 0; e0 < cnt; e0 += 64) {
      int e = e0 + lane;
      float pv = 0.0f;
      if (e < cnt) {
        pv = expf(wt[w][a][e] - mx);
        wt[w][a][e] = pv;
      }
      sum += pv;
    }
#pragma unroll
    for (int o = 1; o < 64; o <<= 1) sum += __shfl_xor(sum, o);
    float inv = (cnt > 0) ? 1.0f / sum : 0.0f;

    // --- gather: 8 edges (16 loads) in flight ---
    float acc0 = 0.0f, acc1 = 0.0f;
    int e = 0;
    for (; e + 8 <= cnt; e += 8) {
      const float* rp[8];
      float wg[8];
#pragma unroll
      for (int q = 0; q < 8; q++) {
        rp[q] = h + (size_t)ej[w][a][e + q] * FD;
        wg[q] = wt[w][a][e + q] * inv;
      }
      float va[8], vb[8];
#pragma unroll
      for (int q = 0; q < 8; q++) {
        va[q] = rp[q][lane];
        vb[q] = rp[q][64 + lane];
      }
#pragma unroll
      for (int q = 0; q < 8; q++) {
        acc0 += wg[q] * va[q];
        acc1 += wg[q] * vb[q];
      }
    }
    for (; e + 4 <= cnt; e += 4) {
      const float* r0 = h + (size_t)ej[w][a][e + 0] * FD;
      const float* r1 = h + (size_t)ej[w][a][e + 1] * FD;
      const float* r2 = h + (size_t)ej[w][a][e + 2] * FD;
      const float* r3 = h + (size_t)ej[w][a][e + 3] * FD;
      float w0 = wt[w][a][e + 0] * inv, w1 = wt[w][a][e + 1] * inv;
      float w2 = wt[w][a][e + 2] * inv, w3 = wt[w][a][e + 3] * inv;
      acc0 += w0 * r0[lane] + w1 * r1[lane] + w2 * r2[lane] + w3 * r3[lane];
      acc1 += w0 * r0[64 + lane] + w1 * r1[64 + lane] + w2 * r2[64 + lane] + w3 * r3[64 + lane];
    }
    for (; e < cnt; e++) {
      float wg = wt[w][a][e] * inv;
      const float* hr = h + (size_t)ej[w][a][e] * FD;
      acc0 += wg * hr[lane];
      acc1 += wg * hr[64 + lane];
    }
    ga[a][0] = acc0;
    ga[a][1] = acc1;
  }

  // --- combine: out = tanh(hs) + tanh(gu) + tanh(gd) + tanh(sum hp) ---
  const float* hs = hmat + ((size_t)(d * 3) * NN + i) * FD;
  const float* h0 = hp + ((size_t)(d * 4 + 0) * NN + i) * FD;
  const float* h1 = hp + ((size_t)(d * 4 + 1) * NN + i) * FD;
  const float* h2 = hp + ((size_t)(d * 4 + 2) * NN + i) * FD;
  const float* h3 = hp + ((size_t)(d * 4 + 3) * NN + i) * FD;
  float* o = out + ((size_t)d * NN + i) * FD;
#pragma unroll
  for (int hf = 0; hf < 2; hf++) {
    int col = hf * 64 + lane;
    float ps = h0[col] + h1[col] + h2[col] + h3[col];
    o[col] = tanhf(hs[col]) + tanhf(ga[0][hf]) + tanhf(ga[1][hf]) + tanhf(ps);
  }
}

extern "C" void kernel_launch(void* const* d_in, const int* in_sizes, int n_in,
                              void* d_out, int out_size, void* d_ws, size_t ws_size,
                              hipStream_t stream) {
  const float* X   = (const float*)d_in[0];
  const float* L   = (const float*)d_in[1];
  const float* Lu  = (const float*)d_in[2];
  const float* Ldn = (const float*)d_in[3];
  const float* Wp  = (const float*)d_in[4];
  const float* Wsm = (const float*)d_in[5];
  const float* Wu  = (const float*)d_in[6];
  const float* au1 = (const float*)d_in[7];
  const float* au2 = (const float*)d_in[8];
  const float* Wd  = (const float*)d_in[9];
  const float* ad1 = (const float*)d_in[10];
  const float* ad2 = (const float*)d_in[11];
  float* out = (float*)d_out;
  float* ws = (float*)d_ws;

  float* hmat = ws + OFF_HMAT;
  float* svec = ws + OFF_SVEC;
  float* hp   = ws + OFF_HP;
  _Float16* h0T = (_Float16*)(ws + OFF_H0T);
  u64* mask = (u64*)(ws + OFF_MASK);

  k_xw<<<dim3(NN / 64, 4, NDIM), 256, 0, stream>>>(
      X, Wp, Wsm, Wu, Wd, au1, au2, ad1, ad2, hmat, h0T, svec);
  k_mega<<<dim3(512 + 8192, 1, 1), 256, 0, stream>>>(L, h0T, hp, Lu, Ldn, mask);
  k_gatc<<<dim3(NN / 4, NDIM, 1), 256, 0, stream>>>(mask, hmat, svec, hp, out);
}

// Round 11
// 124.387 us; speedup vs baseline: 1.0468x; 1.0468x over previous
//
#include <hip/hip_runtime.h>
#include <hip/hip_bf16.h>

#define NN 4096
#define FD 128
#define NDIM 2
#define CAP 256

typedef unsigned long long u64;

// ---------- workspace layout (float offsets) ----------
// hmat [2][3][4096][128] fp32 : q=0 X@Ws (h_s), q=1 X@Wu, q=2 X@Wd
// svec [2][4][4096]           : v=0 s1u, 1 s2u, 2 s1d, 3 s2d
// hp   [2][4][4096][128] fp32 : split-K partials of L@h0
// h0T  [2][128][4096] f16     : (X@Wp) transposed, f16 (B operand of L-GEMM)
// mask [2][2][4096][64] u64   : bit-packed adjacency (bit l of word w: col=(w>>2)*256+4l+(w&3))
#define OFF_HMAT 0
#define OFF_SVEC 3145728
#define OFF_HP   3178496
#define OFF_H0T  7372800
#define OFF_MASK 7897088

typedef _Float16 f16x8 __attribute__((ext_vector_type(8)));
typedef float f32x4 __attribute__((ext_vector_type(4)));
typedef float f32x4v __attribute__((ext_vector_type(4)));
typedef unsigned long long u64x2 __attribute__((ext_vector_type(2)));

union P4 { _Float16 h[4]; int2 i2; };

__device__ __forceinline__ float f4get(const float4& v, int j) {
    return j == 0 ? v.x : j == 1 ? v.y : j == 2 ? v.z : v.w;
}

// ===================== K1: xw+svec (blocks 0..511)  ||  pack (512..8703) ====
__global__ __launch_bounds__(256) void k_a(
    const float* __restrict__ X, const float* __restrict__ Wp,
    const float* __restrict__ Wsm, const float* __restrict__ Wu,
    const float* __restrict__ Wd, const float* __restrict__ au1,
    const float* __restrict__ au2, const float* __restrict__ ad1,
    const float* __restrict__ ad2, float* __restrict__ hmat,
    _Float16* __restrict__ h0T, float* __restrict__ svec,
    const float* __restrict__ Lu, const float* __restrict__ Ldn,
    u64* __restrict__ mask) {
  __shared__ int4 sm4[3072];  // 48 KB (xw path): As 16 KB + Bs 32 KB
  int t = threadIdx.x, w = t >> 6, lane = t & 63;

  if (blockIdx.x < 512) {
    // ---------------- xw path: h = X @ W_p, tile 64x128, K=128 ----------------
    int b = blockIdx.x;
    int r0 = (b & 63) * 64, p = (b >> 6) & 3, d = b >> 8;
    const float* W = (p == 0 ? Wp : p == 1 ? Wsm : p == 2 ? Wu : Wd) + (size_t)d * FD * FD;
    const float* Xd = X + ((size_t)d * NN + r0) * FD;
    char* As = (char*)sm4;             // 16 KB: X[64 rows][128 k] f16
    char* Bs = (char*)(sm4 + 1024);    // 32 KB: Wt[128 n][128 k] f16

#pragma unroll 4
    for (int u = 0; u < 8; u++) {
      int id = t + u * 256;
      int row = id >> 5, k4 = (id & 31) * 4;
      float4 v = *(const float4*)(Xd + (size_t)row * FD + k4);
      P4 pk;
      pk.h[0] = (_Float16)v.x; pk.h[1] = (_Float16)v.y;
      pk.h[2] = (_Float16)v.z; pk.h[3] = (_Float16)v.w;
      int off = (row * 256 + k4 * 2) ^ ((row & 7) << 4);
      *(int2*)(As + off) = pk.i2;
    }
#pragma unroll 4
    for (int u = 0; u < 16; u++) {
      int id = t + u * 256;
      int k = id >> 5, n4 = (id & 31) * 4;
      float4 v = *(const float4*)(W + (size_t)k * FD + n4);
#pragma unroll
      for (int j = 0; j < 4; j++) {
        int n = n4 + j;
        int off = (n * 256 + k * 2) ^ ((n & 7) << 4);
        *(_Float16*)(Bs + off) = (_Float16)f4get(v, j);
      }
    }
    __syncthreads();

    int lr = lane & 15, lkb = (lane >> 4) * 16;
    f32x4 acc[8] = {};
#pragma unroll
    for (int kb = 0; kb < 4; kb++) {
      int row = w * 16 + lr;
      int offA = (row * 256 + kb * 64 + lkb) ^ ((row & 7) << 4);
      f16x8 a = *(const f16x8*)(As + offA);
      f16x8 bb[8];
#pragma unroll
      for (int n = 0; n < 8; n++) {
        int rn = n * 16 + lr;
        int off = (rn * 256 + kb * 64 + lkb) ^ ((rn & 7) << 4);
        bb[n] = *(const f16x8*)(Bs + off);
      }
#pragma unroll
      for (int n = 0; n < 8; n++)
        acc[n] = __builtin_amdgcn_mfma_f32_16x16x32_f16(a, bb[n], acc[n], 0, 0, 0);
    }

    if (p == 0) {
      _Float16* hT = h0T + (size_t)d * FD * NN;
#pragma unroll
      for (int n = 0; n < 8; n++) {
        int col = n * 16 + lr;
        int grow = r0 + w * 16 + (lane >> 4) * 4;
        P4 pk;
#pragma unroll
        for (int r = 0; r < 4; r++) pk.h[r] = (_Float16)acc[n][r];
        *(int2*)(hT + (size_t)col * NN + grow) = pk.i2;
      }
    } else {
      float* o = hmat + ((size_t)(d * 3 + p - 1) * NN + r0) * FD;
#pragma unroll
      for (int n = 0; n < 8; n++)
#pragma unroll
        for (int r = 0; r < 4; r++)
          o[(size_t)(w * 16 + (lane >> 4) * 4 + r) * FD + n * 16 + lr] = acc[n][r];
      if (p >= 2) {
        const float* a1 = (p == 2 ? au1 : ad1) + (size_t)d * FD;
        const float* a2 = (p == 2 ? au2 : ad2) + (size_t)d * FD;
        float av1[8], av2[8];
#pragma unroll
        for (int n = 0; n < 8; n++) {
          av1[n] = a1[n * 16 + lr];
          av2[n] = a2[n * 16 + lr];
        }
        int vb = (d * 4 + (p - 2) * 2);
#pragma unroll
        for (int r = 0; r < 4; r++) {
          float p1 = 0.0f, p2 = 0.0f;
#pragma unroll
          for (int n = 0; n < 8; n++) {
            p1 += acc[n][r] * av1[n];
            p2 += acc[n][r] * av2[n];
          }
#pragma unroll
          for (int o2 = 1; o2 < 16; o2 <<= 1) {
            p1 += __shfl_xor(p1, o2);
            p2 += __shfl_xor(p2, o2);
          }
          if (lr == 0) {
            int row = r0 + w * 16 + (lane >> 4) * 4 + r;
            svec[(size_t)vb * NN + row] = p1;
            svec[(size_t)(vb + 1) * NN + row] = p2;
          }
        }
      }
    }
    return;
  }

  // ---------------- pack path: wave = one half-row (2048 cols, 8 KB), nt ---
  int hr = (blockIdx.x - 512) * 4 + w;       // [0, 32768)
  int p = hr >> 13;                          // plane: d = p>>1, a = p&1
  int rq = hr & 8191;
  int row = rq >> 1, half = rq & 1;
  const float* src = ((p & 1) ? Ldn : Lu) +
                     ((size_t)(p >> 1) * NN + row) * (size_t)NN + half * 2048;
  f32x4v v[8];
#pragma unroll
  for (int q = 0; q < 4; q++) {
    const f32x4v* s4 = (const f32x4v*)(src + q * 512);
    v[2 * q]     = __builtin_nontemporal_load(s4 + lane);
    v[2 * q + 1] = __builtin_nontemporal_load(s4 + 64 + lane);
  }
  u64* o = mask + ((size_t)p * NN + row) * 64 + half * 32;
#pragma unroll
  for (int q = 0; q < 4; q++) {
    u64 m0 = __ballot(v[2 * q][0] == 1.0f);
    u64 m1 = __ballot(v[2 * q][1] == 1.0f);
    u64 m2 = __ballot(v[2 * q][2] == 1.0f);
    u64 m3 = __ballot(v[2 * q][3] == 1.0f);
    u64 m4 = __ballot(v[2 * q + 1][0] == 1.0f);
    u64 m5 = __ballot(v[2 * q + 1][1] == 1.0f);
    u64 m6 = __ballot(v[2 * q + 1][2] == 1.0f);
    u64 m7 = __ballot(v[2 * q + 1][3] == 1.0f);
    if (lane == 0) {
      u64x2 a0 = {m0, m1}, a1 = {m2, m3}, a2 = {m4, m5}, a3 = {m6, m7};
      __builtin_nontemporal_store(a0, (u64x2*)(o + q * 8 + 0));
      __builtin_nontemporal_store(a1, (u64x2*)(o + q * 8 + 2));
      __builtin_nontemporal_store(a2, (u64x2*)(o + q * 8 + 4));
      __builtin_nontemporal_store(a3, (u64x2*)(o + q * 8 + 6));
    }
  }
}

// ===================== K2: lgemm (blocks 0..511)  ||  gat' (512..2559) ======
__global__ __launch_bounds__(256) void k_b(
    const float* __restrict__ L, const _Float16* __restrict__ h0T,
    float* __restrict__ hp, const u64* __restrict__ mask,
    const float* __restrict__ hmat, const float* __restrict__ svec,
    float* __restrict__ out) {
  __shared__ int4 sm4[1536];  // 24 KB: lgemm As 8 KB + Bs 16 KB; gat uses 16 KB
  int t = threadIdx.x, w = t >> 6, lane = t & 63;

  if (blockIdx.x < 512) {
    // ---------------- lgemm path (BK=64, R9-proven, conflict-free) ----------
    int b = blockIdx.x;
    int r0 = (b & 63) * 64, ks = (b >> 6) & 3, d = b >> 8;
    const float* Lr = L + (size_t)d * NN * NN;
    const _Float16* hT = h0T + (size_t)d * FD * NN;
    char* As = (char*)sm4;            //  8 KB: A[64 rows][64 k] f16
    char* Bs = (char*)(sm4 + 512);    // 16 KB: Bt[128 n][64 k] f16
    int lr = lane & 15, lkb = (lane >> 4) * 16;
    f32x4 acc[8] = {};
    int kbeg = ks * 1024;
    for (int kk = kbeg; kk < kbeg + 1024; kk += 64) {
#pragma unroll
      for (int u = 0; u < 4; u++) {
        int id = t + u * 256;
        int row = id >> 4, k4 = (id & 15) * 4;
        f32x4v v = __builtin_nontemporal_load(
            (const f32x4v*)(Lr + (size_t)(r0 + row) * NN + kk) + (k4 >> 2));
        P4 pk;
        pk.h[0] = (_Float16)v[0]; pk.h[1] = (_Float16)v[1];
        pk.h[2] = (_Float16)v[2]; pk.h[3] = (_Float16)v[3];
        int off = (row * 128 + k4 * 2) ^ ((row & 7) << 4);
        *(int2*)(As + off) = pk.i2;
      }
#pragma unroll
      for (int u = 0; u < 4; u++) {
        int id = t + u * 256;
        int n = id >> 3, k8 = (id & 7) * 8;
        int4 v = *(const int4*)(hT + (size_t)n * NN + kk + k8);
        int off = (n * 128 + k8 * 2) ^ ((n & 7) << 4);
        *(int4*)(Bs + off) = v;
      }
      __syncthreads();
#pragma unroll
      for (int kb = 0; kb < 2; kb++) {
        int row = w * 16 + lr;
        int offA = (row * 128 + kb * 64 + lkb) ^ ((row & 7) << 4);
        f16x8 a = *(const f16x8*)(As + offA);
        f16x8 bb[8];
#pragma unroll
        for (int n = 0; n < 8; n++) {
          int rn = n * 16 + lr;
          int off = (rn * 128 + kb * 64 + lkb) ^ ((rn & 7) << 4);
          bb[n] = *(const f16x8*)(Bs + off);
        }
#pragma unroll
        for (int n = 0; n < 8; n++)
          acc[n] = __builtin_amdgcn_mfma_f32_16x16x32_f16(a, bb[n], acc[n], 0, 0, 0);
      }
      __syncthreads();
    }
    float* o = hp + ((size_t)(d * 4 + ks) * NN + r0) * FD;
#pragma unroll
    for (int n = 0; n < 8; n++)
#pragma unroll
      for (int r = 0; r < 4; r++)
        o[(size_t)(w * 16 + (lane >> 4) * 4 + r) * FD + n * 16 + lr] = acc[n][r];
    return;
  }

  // ---------------- gat' path: wave per row, both adjacencies + partial out -
  int idx = blockIdx.x - 512;          // [0, 2048)
  int d = idx >> 10;
  int i = (idx & 1023) * 4 + w;
  int* ej = (int*)sm4;                     // [4][2][CAP] ints = 8 KB
  float* wt = (float*)(sm4 + 512);         // [4][2][CAP] floats = 8 KB

  u64 mm0 = mask[((size_t)((d * 2 + 0) * NN) + i) * 64 + lane];
  u64 mm1 = mask[((size_t)((d * 2 + 1) * NN) + i) * 64 + lane];

  float ga[2][2];  // [a][half]
#pragma unroll
  for (int a = 0; a < 2; a++) {
    const float* h = hmat + (size_t)(d * 3 + 1 + a) * NN * FD;
    const float* s1 = svec + (size_t)(d * 4 + 2 * a) * NN;
    const float* s2 = svec + (size_t)(d * 4 + 2 * a + 1) * NN;
    int* ejw = ej + (w * 2 + a) * CAP;
    float* wtw = wt + (w * 2 + a) * CAP;

    u64 m = a == 0 ? mm0 : mm1;
    int c = __popcll(m);
    int pre = c;
#pragma unroll
    for (int o = 1; o < 64; o <<= 1) {
      int tv = __shfl_up(pre, o);
      if (lane >= o) pre += tv;
    }
    int cnt = __shfl(pre, 63);
    int base = pre - c;
    int colbase = (lane >> 2) * 256 + (lane & 3);
    while (m) {
      int b = __ffsll((unsigned long long)m) - 1;
      m &= m - 1;
      if (base < CAP) ejw[base] = colbase + b * 4;
      base++;
    }
    cnt = min(cnt, CAP);

    float s1i = s1[i];
    float mx = -1e30f;
    for (int e0 = 0; e0 < cnt; e0 += 64) {
      int e = e0 + lane;
      float sc = -1e30f;
      if (e < cnt) {
        int j = ejw[e];
        float x = s1i + s2[j];
        sc = x > 0.0f ? x : 0.01f * x;
        wtw[e] = sc;
      }
      mx = fmaxf(mx, sc);
    }
#pragma unroll
    for (int o = 1; o < 64; o <<= 1) mx = fmaxf(mx, __shfl_xor(mx, o));
    float sum = 0.0f;
    for (int e0 = 0; e0 < cnt; e0 += 64) {
      int e = e0 + lane;
      float pv = 0.0f;
      if (e < cnt) {
        pv = expf(wtw[e] - mx);
        wtw[e] = pv;
      }
      sum += pv;
    }
#pragma unroll
    for (int o = 1; o < 64; o <<= 1) sum += __shfl_xor(sum, o);
    float inv = (cnt > 0) ? 1.0f / sum : 0.0f;

    float acc0 = 0.0f, acc1 = 0.0f;
    int e = 0;
    for (; e + 8 <= cnt; e += 8) {
      const float* rp[8];
      float wg[8];
#pragma unroll
      for (int q = 0; q < 8; q++) {
        rp[q] = h + (size_t)ejw[e + q] * FD;
        wg[q] = wtw[e + q] * inv;
      }
      float va[8], vb[8];
#pragma unroll
      for (int q = 0; q < 8; q++) {
        va[q] = rp[q][lane];
        vb[q] = rp[q][64 + lane];
      }
#pragma unroll
      for (int q = 0; q < 8; q++) {
        acc0 += wg[q] * va[q];
        acc1 += wg[q] * vb[q];
      }
    }
    for (; e + 4 <= cnt; e += 4) {
      const float* r0 = h + (size_t)ejw[e + 0] * FD;
      const float* r1 = h + (size_t)ejw[e + 1] * FD;
      const float* r2 = h + (size_t)ejw[e + 2] * FD;
      const float* r3 = h + (size_t)ejw[e + 3] * FD;
      float w0 = wtw[e + 0] * inv, w1 = wtw[e + 1] * inv;
      float w2 = wtw[e + 2] * inv, w3 = wtw[e + 3] * inv;
      acc0 += w0 * r0[lane] + w1 * r1[lane] + w2 * r2[lane] + w3 * r3[lane];
      acc1 += w0 * r0[64 + lane] + w1 * r1[64 + lane] + w2 * r2[64 + lane] + w3 * r3[64 + lane];
    }
    for (; e < cnt; e++) {
      float wg = wtw[e] * inv;
      const float* hr = h + (size_t)ejw[e] * FD;
      acc0 += wg * hr[lane];
      acc1 += wg * hr[64 + lane];
    }
    ga[a][0] = acc0;
    ga[a][1] = acc1;
  }

  // partial combine (hp added by k_ep): out = tanh(hs) + tanh(gu) + tanh(gd)
  const float* hs = hmat + ((size_t)(d * 3) * NN + i) * FD;
  float* o = out + ((size_t)d * NN + i) * FD;
#pragma unroll
  for (int hf = 0; hf < 2; hf++) {
    int col = hf * 64 + lane;
    o[col] = tanhf(hs[col]) + tanhf(ga[0][hf]) + tanhf(ga[1][hf]);
  }
}

// ===================== K3: epilogue  out += tanh(sum hp) ====================
__global__ __launch_bounds__(256) void k_ep(
    const float* __restrict__ hp, float* __restrict__ out) {
  const size_t tot4 = (size_t)NDIM * NN * FD / 4;
  for (size_t i4 = (size_t)blockIdx.x * blockDim.x + threadIdx.x; i4 < tot4;
       i4 += (size_t)gridDim.x * blockDim.x) {
    size_t i = i4 * 4;
    int d = (int)(i >> 19);
    size_t rem = i & 524287;
    float4 p0 = *(const float4*)(hp + ((size_t)(d * 4 + 0) << 19) + rem);
    float4 p1 = *(const float4*)(hp + ((size_t)(d * 4 + 1) << 19) + rem);
    float4 p2 = *(const float4*)(hp + ((size_t)(d * 4 + 2) << 19) + rem);
    float4 p3 = *(const float4*)(hp + ((size_t)(d * 4 + 3) << 19) + rem);
    float4 o = *(const float4*)(out + i);
    o.x += tanhf(p0.x + p1.x + p2.x + p3.x);
    o.y += tanhf(p0.y + p1.y + p2.y + p3.y);
    o.z += tanhf(p0.z + p1.z + p2.z + p3.z);
    o.w += tanhf(p0.w + p1.w + p2.w + p3.w);
    *(float4*)(out + i) = o;
  }
}

extern "C" void kernel_launch(void* const* d_in, const int* in_sizes, int n_in,
                              void* d_out, int out_size, void* d_ws, size_t ws_size,
                              hipStream_t stream) {
  const float* X   = (const float*)d_in[0];
  const float* L   = (const float*)d_in[1];
  const float* Lu  = (const float*)d_in[2];
  const float* Ldn = (const float*)d_in[3];
  const float* Wp  = (const float*)d_in[4];
  const float* Wsm = (const float*)d_in[5];
  const float* Wu  = (const float*)d_in[6];
  const float* au1 = (const float*)d_in[7];
  const float* au2 = (const float*)d_in[8];
  const float* Wd  = (const float*)d_in[9];
  const float* ad1 = (const float*)d_in[10];
  const float* ad2 = (const float*)d_in[11];
  float* out = (float*)d_out;
  float* ws = (float*)d_ws;

  float* hmat = ws + OFF_HMAT;
  float* svec = ws + OFF_SVEC;
  float* hp   = ws + OFF_HP;
  _Float16* h0T = (_Float16*)(ws + OFF_H0T);
  u64* mask = (u64*)(ws + OFF_MASK);

  k_a<<<dim3(512 + 8192, 1, 1), 256, 0, stream>>>(
      X, Wp, Wsm, Wu, Wd, au1, au2, ad1, ad2, hmat, h0T, svec, Lu, Ldn, mask);
  k_b<<<dim3(512 + 2048, 1, 1), 256, 0, stream>>>(
      L, h0T, hp, mask, hmat, svec, out);
  k_ep<<<1024, 256, 0, stream>>>(hp, out);
}